// Round 9
// baseline (197.177 us; speedup 1.0000x reference)
//
#include <hip/hip_runtime.h>

// MultiHeadSelfAttention  B=2 S=2048 E=512 H=8 D=64, fp32 in/out.
// R9 = R6 proj/outproj (verbatim) + attn rebuilt on 32x32x16 MFMAs:
//   - S^T = K Q^T per 32-key tile (f16), fixed-shift softmax p=exp(s-64),
//     P packed b64 into per-wave LDS, PV + via 32x32x16 bf16.
//   - row-sums l via VALU adds on score regs + one shfl_xor(32) (no MFMA/LDS).
//   - register-prefetch staging (global->VGPR->LDS), 2 waves/block, 512 blocks.
// Layouts: 16x16 (verified m89/m91): A[m=lane&15][k=quad*8+j], D[row=quad*4+reg][col=lane&15].
//   32x32 C/D (verified m74/m101): col=lane&31, row=(reg&3)+8*(reg>>2)+4*(lane>>5).
//   32x32 A/B (gfx950 doubling pattern): own-index=lane&31, k=(lane>>5)*8+j.
// Workspace: qf,kf (fp16) + vt,ctx (bf16) = 4 x 4 MB = 16 MB.

#define B_ 2
#define S_ 2048
#define E_ 512
#define H_ 8
#define D_ 64

typedef unsigned short ushort_t;
typedef __attribute__((ext_vector_type(8))) short short8;
typedef __attribute__((ext_vector_type(8))) _Float16 half8;
typedef __attribute__((ext_vector_type(4))) float f32x4;
typedef __attribute__((ext_vector_type(16))) float f32x16;

__device__ __forceinline__ ushort_t f2bs(float x) {   // fp32 -> bf16 bits, RNE
    union { float f; unsigned int u; } a; a.f = x;
    unsigned int u = a.u;
    u += 0x7fffu + ((u >> 16) & 1u);
    return (ushort_t)(u >> 16);
}
__device__ __forceinline__ ushort_t f2bs_fast(float x) {   // round-half-up (P only)
    union { float f; unsigned int u; } a; a.f = x;
    return (ushort_t)((a.u + 0x8000u) >> 16);
}
__device__ __forceinline__ float bs2f(ushort_t h) {
    union { unsigned int u; float f; } a; a.u = ((unsigned int)h) << 16;
    return a.f;
}
__device__ __forceinline__ ushort_t f2hs(float x) {   // fp32 -> fp16 bits
    _Float16 h = (_Float16)x;
    ushort_t u; __builtin_memcpy(&u, &h, 2);
    return u;
}
// split 16 fp32 into bf16 hi + bf16 lo (residual)
__device__ __forceinline__ void split16(const float4* g, ushort_t* hi, ushort_t* lo) {
    #pragma unroll
    for (int q = 0; q < 4; ++q) {
        float4 f = g[q];
        float vv[4] = {f.x, f.y, f.z, f.w};
        #pragma unroll
        for (int j = 0; j < 4; ++j) {
            ushort_t h = f2bs(vv[j]);
            hi[q * 4 + j] = h;
            lo[q * 4 + j] = f2bs(vv[j] - bs2f(h));
        }
    }
}

// ---------------- Kernel 1: split-precision projection (R6 verbatim) ----------------
__global__ void __launch_bounds__(256) proj_mfma(
    const float* __restrict__ quer, const float* __restrict__ keys,
    const float* __restrict__ vals, const float* __restrict__ Wv,
    ushort_t* __restrict__ qf, ushort_t* __restrict__ kf,
    ushort_t* __restrict__ vt)
{
    __shared__ ushort_t Ah[64 * 72], Al[64 * 72];
    __shared__ ushort_t Bh[64 * 72], Bl[64 * 72];
    const int tens = blockIdx.y;
    const float* src = tens == 0 ? quer : (tens == 1 ? keys : vals);
    const int bx = blockIdx.x;            // bh*32 + st
    const int st = bx & 31, bh = bx >> 5;
    const int b = bh >> 3, h = bh & 7;
    const int s0 = st * 64;
    const int t = threadIdx.x;

    {   // Wv -> Bh/Bl [e][d]   (B[k=d][n=e])
        int e = t >> 2, dg = (t & 3) * 16;
        ushort_t th[16], tl[16];
        split16((const float4*)(Wv + e * 64 + dg), th, tl);
        *(uint4*)&Bh[e * 72 + dg] = *(uint4*)th;  *(uint4*)&Bh[e * 72 + dg + 8] = *(uint4*)(th + 8);
        *(uint4*)&Bl[e * 72 + dg] = *(uint4*)tl;  *(uint4*)&Bl[e * 72 + dg + 8] = *(uint4*)(tl + 8);
    }
    {   // x rows (s0..s0+63) -> Ah/Al [s][d]
        int row = t >> 2, cg = (t & 3) * 16;
        const float* g = src + ((size_t)b * S_ + s0 + row) * 512 + h * 64 + cg;
        ushort_t th[16], tl[16];
        split16((const float4*)g, th, tl);
        *(uint4*)&Ah[row * 72 + cg] = *(uint4*)th;  *(uint4*)&Ah[row * 72 + cg + 8] = *(uint4*)(th + 8);
        *(uint4*)&Al[row * 72 + cg] = *(uint4*)tl;  *(uint4*)&Al[row * 72 + cg + 8] = *(uint4*)(tl + 8);
    }
    __syncthreads();

    const int w = t >> 6, lm = t & 15, quad = (t >> 4) & 3;
    f32x4 acc[4];
    #pragma unroll
    for (int nt = 0; nt < 4; ++nt) acc[nt] = (f32x4){0.f, 0.f, 0.f, 0.f};

    #pragma unroll
    for (int kk = 0; kk < 2; ++kk) {
        short8 ah = *(const short8*)&Ah[(w * 16 + lm) * 72 + kk * 32 + quad * 8];
        short8 al = *(const short8*)&Al[(w * 16 + lm) * 72 + kk * 32 + quad * 8];
        #pragma unroll
        for (int nt = 0; nt < 4; ++nt) {
            short8 bh8 = *(const short8*)&Bh[(nt * 16 + lm) * 72 + kk * 32 + quad * 8];
            short8 bl8 = *(const short8*)&Bl[(nt * 16 + lm) * 72 + kk * 32 + quad * 8];
            acc[nt] = __builtin_amdgcn_mfma_f32_16x16x32_bf16(ah, bh8, acc[nt], 0, 0, 0);
            acc[nt] = __builtin_amdgcn_mfma_f32_16x16x32_bf16(al, bh8, acc[nt], 0, 0, 0);
            acc[nt] = __builtin_amdgcn_mfma_f32_16x16x32_bf16(ah, bl8, acc[nt], 0, 0, 0);
        }
    }

    if (tens < 2) {       // q,k: store single fp16, layout (bh, s, d)
        ushort_t* dst = tens == 0 ? qf : kf;
        #pragma unroll
        for (int nt = 0; nt < 4; ++nt)
            #pragma unroll
            for (int r = 0; r < 4; ++r) {
                size_t addr = ((size_t)bh * S_ + s0 + w * 16 + quad * 4 + r) * 64 + nt * 16 + lm;
                dst[addr] = f2hs(acc[nt][r]);
            }
    } else {              // v: store bf16 transposed (bh, d, s) -> 8B packed stores
        #pragma unroll
        for (int nt = 0; nt < 4; ++nt) {
            unsigned int p0 = (unsigned int)f2bs(acc[nt][0]) | ((unsigned int)f2bs(acc[nt][1]) << 16);
            unsigned int p1 = (unsigned int)f2bs(acc[nt][2]) | ((unsigned int)f2bs(acc[nt][3]) << 16);
            uint2 pk; pk.x = p0; pk.y = p1;
            size_t addr = ((size_t)bh * 64 + nt * 16 + lm) * S_ + s0 + w * 16 + quad * 4;
            *(uint2*)&vt[addr] = pk;
        }
    }
}

// ---------------- Kernel 2: flash attention (32x32x16 MFMA) ----------------
#define KSTR 72
#define VSTR 72
#define PSTR 72
__global__ void __launch_bounds__(128) attn_mfma(
    const ushort_t* __restrict__ qf, const ushort_t* __restrict__ kf,
    const ushort_t* __restrict__ vt, const int* __restrict__ mask,
    ushort_t* __restrict__ ctx)
{
    __shared__ ushort_t Ks[64 * KSTR];        // fp16 K tile [key][d]
    __shared__ ushort_t Vt[64 * VSTR];        // bf16 V tile [d][key]
    __shared__ ushort_t Ps[2][32 * PSTR];     // per-wave P [q][key] bf16
    __shared__ float    linv[2][32];

    const int bx = blockIdx.x;
    const int qt = bx & 31;                   // 32 q-tiles of 64
    const int bh = bx >> 5;
    const int b  = bh >> 3, hd = bh & 7;
    const int t  = threadIdx.x;
    const int w  = t >> 6;                    // wave 0/1
    const int lane = t & 63;
    const int lm = lane & 31;                 // 32-row index
    const int hh = lane >> 5;                 // k-half
    const int q0 = qt * 64 + w * 32;          // this wave's 32 queries

    // Q B-frags (4 k-slices of d), held in regs all kernel
    half8 qfr[4];
    {
        size_t base = ((size_t)bh * S_ + q0 + lm) * 64 + hh * 8;
        #pragma unroll
        for (int ksl = 0; ksl < 4; ++ksl)
            qfr[ksl] = *(const half8*)&qf[base + ksl * 16];
    }

    f32x16 acc[2];
    #pragma unroll
    for (int dt = 0; dt < 2; ++dt)
        #pragma unroll
        for (int i = 0; i < 16; ++i) acc[dt][i] = 0.f;
    float ls = 0.f;

    // staging: 128 thr, each 32 shorts (4 uint4) per tile
    const int srow = t >> 1, scg = (t & 1) * 32;
    const ushort_t* kg = &kf[((size_t)bh * S_ + srow) * 64 + scg];
    const ushort_t* vg = &vt[((size_t)bh * 64 + srow) * S_ + scg];

    uint4 kreg[4], vreg[4];
    {
        #pragma unroll
        for (int j = 0; j < 4; ++j) {
            kreg[j] = *(const uint4*)&kg[j * 8];
            vreg[j] = *(const uint4*)&vg[j * 8];
        }
    }

    for (int kc = 0; kc < 32; ++kc) {
        __syncthreads();
        #pragma unroll
        for (int j = 0; j < 4; ++j) {
            *(uint4*)&Ks[srow * KSTR + scg + j * 8] = kreg[j];
            *(uint4*)&Vt[srow * VSTR + scg + j * 8] = vreg[j];
        }
        __syncthreads();
        if (kc + 1 < 32) {   // prefetch next chunk into regs (in flight over compute)
            const ushort_t* kp = kg + (size_t)(kc + 1) * 64 * 64;
            const ushort_t* vp = vg + (size_t)(kc + 1) * 64;
            #pragma unroll
            for (int j = 0; j < 4; ++j) {
                kreg[j] = *(const uint4*)&kp[j * 8];
                vreg[j] = *(const uint4*)&vp[j * 8];
            }
        }

        const int mbase = b * S_ + kc * 64;
        // ---- S^T = K Q^T per 32-key tile; p = exp(s+bias); packed b64 P ----
        #pragma unroll
        for (int mt = 0; mt < 2; ++mt) {
            f32x16 s;
            #pragma unroll
            for (int i = 0; i < 16; ++i) s[i] = 0.f;
            #pragma unroll
            for (int ksl = 0; ksl < 4; ++ksl) {
                half8 ak = *(const half8*)&Ks[(mt * 32 + lm) * KSTR + ksl * 16 + hh * 8];
                s = __builtin_amdgcn_mfma_f32_32x32x16_f16(ak, qfr[ksl], s, 0, 0, 0);
            }
            #pragma unroll
            for (int g = 0; g < 4; ++g) {
                int4 mi = *(const int4*)&mask[mbase + mt * 32 + g * 8 + hh * 4];
                float p0 = __expf(s[g * 4 + 0] + (mi.x ? -64.f : -1e30f));
                float p1 = __expf(s[g * 4 + 1] + (mi.y ? -64.f : -1e30f));
                float p2 = __expf(s[g * 4 + 2] + (mi.z ? -64.f : -1e30f));
                float p3 = __expf(s[g * 4 + 3] + (mi.w ? -64.f : -1e30f));
                ls += (p0 + p1) + (p2 + p3);
                ushort_t p4[4] = {f2bs_fast(p0), f2bs_fast(p1), f2bs_fast(p2), f2bs_fast(p3)};
                *(uint2*)&Ps[w][lm * PSTR + mt * 32 + g * 8 + hh * 4] = *(uint2*)p4;
            }
        }
        __asm__ volatile("s_waitcnt lgkmcnt(0)" ::: "memory");

        // ---- O += P V  (A = P rows, B = V^T rows) ----
        #pragma unroll
        for (int ksl = 0; ksl < 4; ++ksl) {
            short8 ap = *(const short8*)&Ps[w][lm * PSTR + ksl * 16 + hh * 8];
            #pragma unroll
            for (int dt = 0; dt < 2; ++dt) {
                short8 bv = *(const short8*)&Vt[(dt * 32 + lm) * VSTR + ksl * 16 + hh * 8];
                acc[dt] = __builtin_amdgcn_mfma_f32_32x32x16_bf16(ap, bv, acc[dt], 0, 0, 0);
            }
        }
    }

    // ---- finalize ----
    ls += __shfl_xor(ls, 32);
    if (hh == 0) linv[w][lm] = 1.f / ls;
    __asm__ volatile("s_waitcnt lgkmcnt(0)" ::: "memory");
    float li[16];
    #pragma unroll
    for (int r = 0; r < 16; ++r) li[r] = linv[w][(r & 3) + 8 * (r >> 2) + 4 * hh];
    #pragma unroll
    for (int dt = 0; dt < 2; ++dt) {
        #pragma unroll
        for (int r = 0; r < 16; ++r) {
            int s = q0 + (r & 3) + 8 * (r >> 2) + 4 * hh;
            int d = dt * 32 + lm;
            ctx[((size_t)b * S_ + s) * E_ + hd * D_ + d] = f2bs(acc[dt][r] * li[r]);
        }
    }
}

// ---------------- Kernel 3: out = ctx @ Wo^T + bo (R6 verbatim) ----------------
__global__ void __launch_bounds__(256) outproj_mfma(
    const ushort_t* __restrict__ ctx, const float* __restrict__ Wo,
    const float* __restrict__ bo, float* __restrict__ out)
{
    __shared__ ushort_t As[64 * 72];
    __shared__ ushort_t Bs[64 * 72];
    const int m0 = blockIdx.x * 64, n0 = blockIdx.y * 64;
    const int t = threadIdx.x;
    const int w = t >> 6, lm = t & 15, quad = (t >> 4) & 3;

    f32x4 acc[4];
    #pragma unroll
    for (int nt = 0; nt < 4; ++nt) acc[nt] = (f32x4){0.f, 0.f, 0.f, 0.f};

    for (int kc = 0; kc < E_ / 64; ++kc) {
        __syncthreads();
        {   // A: ctx rows (bf16 already)
            int row = t >> 2, cg = (t & 3) * 16;
            const ushort_t* g = ctx + (size_t)(m0 + row) * E_ + kc * 64 + cg;
            *(uint4*)&As[row * 72 + cg]     = *(const uint4*)g;
            *(uint4*)&As[row * 72 + cg + 8] = *(const uint4*)(g + 8);
        }
        {   // B: Bs[n][k] = Wo[n0+n][kc*64+k] (fp32 -> bf16)
            int n = t >> 2, kg = (t & 3) * 16;
            const float4* g = (const float4*)(Wo + (size_t)(n0 + n) * E_ + kc * 64 + kg);
            ushort_t tmp[16];
            #pragma unroll
            for (int q = 0; q < 4; ++q) {
                float4 f = g[q];
                tmp[q * 4 + 0] = f2bs(f.x); tmp[q * 4 + 1] = f2bs(f.y);
                tmp[q * 4 + 2] = f2bs(f.z); tmp[q * 4 + 3] = f2bs(f.w);
            }
            *(uint4*)&Bs[n * 72 + kg]     = *(uint4*)tmp;
            *(uint4*)&Bs[n * 72 + kg + 8] = *(uint4*)(tmp + 8);
        }
        __syncthreads();

        #pragma unroll
        for (int kk = 0; kk < 2; ++kk) {
            short8 a = *(const short8*)&As[(w * 16 + lm) * 72 + kk * 32 + quad * 8];
            #pragma unroll
            for (int nt = 0; nt < 4; ++nt) {
                short8 bb = *(const short8*)&Bs[(nt * 16 + lm) * 72 + kk * 32 + quad * 8];
                acc[nt] = __builtin_amdgcn_mfma_f32_16x16x32_bf16(a, bb, acc[nt], 0, 0, 0);
            }
        }
    }

    #pragma unroll
    for (int nt = 0; nt < 4; ++nt) {
        float bias = bo[n0 + nt * 16 + lm];
        #pragma unroll
        for (int r = 0; r < 4; ++r) {
            int m = m0 + w * 16 + quad * 4 + r;
            out[(size_t)m * E_ + n0 + nt * 16 + lm] = acc[nt][r] + bias;
        }
    }
}

extern "C" void kernel_launch(void* const* d_in, const int* in_sizes, int n_in,
                              void* d_out, int out_size, void* d_ws, size_t ws_size,
                              hipStream_t stream) {
    const float* vals = (const float*)d_in[0];
    const float* keys = (const float*)d_in[1];
    const float* quer = (const float*)d_in[2];
    const int*   mask = (const int*)d_in[3];
    const float* Wv   = (const float*)d_in[4];
    const float* Wo   = (const float*)d_in[5];
    const float* bo   = (const float*)d_in[6];
    float* out = (float*)d_out;

    const size_t N = (size_t)B_ * H_ * S_ * D_;   // 2097152
    ushort_t* ws  = (ushort_t*)d_ws;
    ushort_t* qf  = ws;                 // fp16 (bh, s, d)
    ushort_t* kf  = ws + N;             // fp16 (bh, s, d)
    ushort_t* vt  = ws + 2 * N;         // bf16 (bh, d, s)
    ushort_t* ctx = ws + 3 * N;         // bf16 (b, s, E)

    proj_mfma<<<dim3(B_ * H_ * (S_ / 64), 3), 256, 0, stream>>>(
        quer, keys, vals, Wv, qf, kf, vt);
    attn_mfma<<<B_ * H_ * (S_ / 64), 128, 0, stream>>>(qf, kf, vt, mask, ctx);
    outproj_mfma<<<dim3((B_ * S_) / 64, E_ / 64), 256, 0, stream>>>(ctx, Wo, bo, out);
}

// Round 10
// 191.544 us; speedup vs baseline: 1.0294x; 1.0294x over previous
//
#include <hip/hip_runtime.h>

// MultiHeadSelfAttention  B=2 S=2048 E=512 H=8 D=64, fp32 in/out.
// R10: 32x32x16 attn engine (R9, layouts verified) restored to 8 waves/CU by
//   key-splitting: block = 4 waves = (qsub 0/1) x (keyhalf 0/1); both halves'
//   K/V chunks staged per iter; fixed-shift softmax is linear -> end combine
//   of partial O (fp32, LDS) and l. 512 blocks x 256 thr, LDS 72 KB = 2/CU.
// prep: Wv -> bf16 (hi,lo) split, Wo -> bf16 (once) — proj/outproj stage via
//   plain uint4 copies (no per-block split/convert VALU).
// Layouts (HW-verified): 16x16 A[m=lane&15][k=quad*8+j], D[row=quad*4+reg][col=lane&15];
//   32x32 C/D col=lane&31, row=(reg&3)+8*(reg>>2)+4*(lane>>5); A/B k=(lane>>5)*8+j.
// Workspace: qf,kf (fp16) + vt,ctx (bf16) 4 MB each + wvh/wvl/wob ~0.6 MB.

#define B_ 2
#define S_ 2048
#define E_ 512
#define H_ 8
#define D_ 64

typedef unsigned short ushort_t;
typedef __attribute__((ext_vector_type(8))) short short8;
typedef __attribute__((ext_vector_type(8))) _Float16 half8;
typedef __attribute__((ext_vector_type(4))) float f32x4;
typedef __attribute__((ext_vector_type(16))) float f32x16;

__device__ __forceinline__ ushort_t f2bs(float x) {   // fp32 -> bf16, RNE
    union { float f; unsigned int u; } a; a.f = x;
    unsigned int u = a.u;
    u += 0x7fffu + ((u >> 16) & 1u);
    return (ushort_t)(u >> 16);
}
__device__ __forceinline__ ushort_t f2bs_fast(float x) {   // round-half-up (P only)
    union { float f; unsigned int u; } a; a.f = x;
    return (ushort_t)((a.u + 0x8000u) >> 16);
}
__device__ __forceinline__ float bs2f(ushort_t h) {
    union { unsigned int u; float f; } a; a.u = ((unsigned int)h) << 16;
    return a.f;
}
__device__ __forceinline__ ushort_t f2hs(float x) {
    _Float16 h = (_Float16)x;
    ushort_t u; __builtin_memcpy(&u, &h, 2);
    return u;
}
__device__ __forceinline__ void split16(const float4* g, ushort_t* hi, ushort_t* lo) {
    #pragma unroll
    for (int q = 0; q < 4; ++q) {
        float4 f = g[q];
        float vv[4] = {f.x, f.y, f.z, f.w};
        #pragma unroll
        for (int j = 0; j < 4; ++j) {
            ushort_t h = f2bs(vv[j]);
            hi[q * 4 + j] = h;
            lo[q * 4 + j] = f2bs(vv[j] - bs2f(h));
        }
    }
}

// ---------------- Kernel 0: weight prep (once) ----------------
__global__ void __launch_bounds__(256) prep_kernel(
    const float* __restrict__ Wv, const float* __restrict__ Wo,
    ushort_t* __restrict__ wvh, ushort_t* __restrict__ wvl,
    ushort_t* __restrict__ wob)
{
    const int t = threadIdx.x;
    size_t base = ((size_t)blockIdx.x * 256 + t) * 4;   // Wo: 262144 = 256*256*4
    float4 f = *(const float4*)&Wo[base];
    ushort_t o4[4] = {f2bs(f.x), f2bs(f.y), f2bs(f.z), f2bs(f.w)};
    *(uint2*)&wob[base] = *(uint2*)o4;
    if (blockIdx.x == 0) {
        ushort_t hi[16], lo[16];
        split16((const float4*)(Wv + t * 16), hi, lo);
        *(uint4*)&wvh[t * 16]     = *(uint4*)hi;
        *(uint4*)&wvh[t * 16 + 8] = *(uint4*)(hi + 8);
        *(uint4*)&wvl[t * 16]     = *(uint4*)lo;
        *(uint4*)&wvl[t * 16 + 8] = *(uint4*)(lo + 8);
    }
}

// ---------------- Kernel 1: split-precision projection ----------------
__global__ void __launch_bounds__(256) proj_mfma(
    const float* __restrict__ quer, const float* __restrict__ keys,
    const float* __restrict__ vals,
    const ushort_t* __restrict__ wvh, const ushort_t* __restrict__ wvl,
    ushort_t* __restrict__ qf, ushort_t* __restrict__ kf,
    ushort_t* __restrict__ vt)
{
    __shared__ ushort_t Ah[64 * 72], Al[64 * 72];
    __shared__ ushort_t Bh[64 * 72], Bl[64 * 72];
    const int tens = blockIdx.y;
    const float* src = tens == 0 ? quer : (tens == 1 ? keys : vals);
    const int bx = blockIdx.x;            // bh*32 + st
    const int st = bx & 31, bh = bx >> 5;
    const int b = bh >> 3, h = bh & 7;
    const int s0 = st * 64;
    const int t = threadIdx.x;

    {   // Bh/Bl [e][d] from pre-split global (plain copies)
        int e = t >> 2, dg = (t & 3) * 16;
        size_t wad = (size_t)e * 64 + dg;
        *(uint4*)&Bh[e * 72 + dg]     = *(const uint4*)&wvh[wad];
        *(uint4*)&Bh[e * 72 + dg + 8] = *(const uint4*)&wvh[wad + 8];
        *(uint4*)&Bl[e * 72 + dg]     = *(const uint4*)&wvl[wad];
        *(uint4*)&Bl[e * 72 + dg + 8] = *(const uint4*)&wvl[wad + 8];
    }
    {   // x rows (s0..s0+63) -> Ah/Al [s][d] (split in regs)
        int row = t >> 2, cg = (t & 3) * 16;
        const float* g = src + ((size_t)b * S_ + s0 + row) * 512 + h * 64 + cg;
        ushort_t th[16], tl[16];
        split16((const float4*)g, th, tl);
        *(uint4*)&Ah[row * 72 + cg] = *(uint4*)th;  *(uint4*)&Ah[row * 72 + cg + 8] = *(uint4*)(th + 8);
        *(uint4*)&Al[row * 72 + cg] = *(uint4*)tl;  *(uint4*)&Al[row * 72 + cg + 8] = *(uint4*)(tl + 8);
    }
    __syncthreads();

    const int w = t >> 6, lm = t & 15, quad = (t >> 4) & 3;
    f32x4 acc[4];
    #pragma unroll
    for (int nt = 0; nt < 4; ++nt) acc[nt] = (f32x4){0.f, 0.f, 0.f, 0.f};

    #pragma unroll
    for (int kk = 0; kk < 2; ++kk) {
        short8 ah = *(const short8*)&Ah[(w * 16 + lm) * 72 + kk * 32 + quad * 8];
        short8 al = *(const short8*)&Al[(w * 16 + lm) * 72 + kk * 32 + quad * 8];
        #pragma unroll
        for (int nt = 0; nt < 4; ++nt) {
            short8 bh8 = *(const short8*)&Bh[(nt * 16 + lm) * 72 + kk * 32 + quad * 8];
            short8 bl8 = *(const short8*)&Bl[(nt * 16 + lm) * 72 + kk * 32 + quad * 8];
            acc[nt] = __builtin_amdgcn_mfma_f32_16x16x32_bf16(ah, bh8, acc[nt], 0, 0, 0);
            acc[nt] = __builtin_amdgcn_mfma_f32_16x16x32_bf16(al, bh8, acc[nt], 0, 0, 0);
            acc[nt] = __builtin_amdgcn_mfma_f32_16x16x32_bf16(ah, bl8, acc[nt], 0, 0, 0);
        }
    }

    if (tens < 2) {       // q,k: fp16 (bh, s, d)
        ushort_t* dst = tens == 0 ? qf : kf;
        #pragma unroll
        for (int nt = 0; nt < 4; ++nt)
            #pragma unroll
            for (int r = 0; r < 4; ++r) {
                size_t addr = ((size_t)bh * S_ + s0 + w * 16 + quad * 4 + r) * 64 + nt * 16 + lm;
                dst[addr] = f2hs(acc[nt][r]);
            }
    } else {              // v: bf16 transposed (bh, d, s), 8B packed stores
        #pragma unroll
        for (int nt = 0; nt < 4; ++nt) {
            unsigned int p0 = (unsigned int)f2bs(acc[nt][0]) | ((unsigned int)f2bs(acc[nt][1]) << 16);
            unsigned int p1 = (unsigned int)f2bs(acc[nt][2]) | ((unsigned int)f2bs(acc[nt][3]) << 16);
            uint2 pk; pk.x = p0; pk.y = p1;
            size_t addr = ((size_t)bh * 64 + nt * 16 + lm) * S_ + s0 + w * 16 + quad * 4;
            *(uint2*)&vt[addr] = pk;
        }
    }
}

// ---------------- Kernel 2: flash attention (32x32x16, key-split waves) ----------------
#define KSTR 72
__global__ void __launch_bounds__(256) attn_mfma(
    const ushort_t* __restrict__ qf, const ushort_t* __restrict__ kf,
    const ushort_t* __restrict__ vt, const int* __restrict__ mask,
    ushort_t* __restrict__ ctx)
{
    __shared__ ushort_t Ks[2][64 * KSTR];     // fp16 K [key][d], per key-half
    __shared__ ushort_t Vt[2][64 * KSTR];     // bf16 V [d][key], per key-half
    __shared__ ushort_t Ps[4][32 * KSTR];     // per-wave P [q][key]
    __shared__ float    cbO[2][32][64];       // kh=1 partial O per qsub
    __shared__ float    cbL[2][32];           // kh=1 partial l
    __shared__ float    linv[2][32];

    const int bx = blockIdx.x;
    const int qt = bx & 31;                   // 32 q-tiles of 64
    const int bh = bx >> 5;
    const int b  = bh >> 3, hd = bh & 7;
    const int t  = threadIdx.x;
    const int w  = t >> 6;
    const int qsub = w & 1, kh = w >> 1;
    const int lane = t & 63;
    const int lm = lane & 31;
    const int hh = lane >> 5;
    const int q0 = qt * 64 + qsub * 32;

    // Q B-frags, held all kernel
    half8 qfr[4];
    {
        size_t base = ((size_t)bh * S_ + q0 + lm) * 64 + hh * 8;
        #pragma unroll
        for (int ksl = 0; ksl < 4; ++ksl)
            qfr[ksl] = *(const half8*)&qf[base + ksl * 16];
    }

    f32x16 acc[2];
    #pragma unroll
    for (int dt = 0; dt < 2; ++dt)
        #pragma unroll
        for (int i = 0; i < 16; ++i) acc[dt][i] = 0.f;
    float ls = 0.f;

    // staging: first 128 threads stage half 0, next 128 stage half 1
    const int sh = t >> 7;
    const int tt = t & 127;
    const int srow = tt >> 1, scg = (tt & 1) * 32;
    const ushort_t* kg = &kf[((size_t)bh * S_ + sh * 1024 + srow) * 64 + scg];
    const ushort_t* vg = &vt[((size_t)bh * 64 + srow) * S_ + sh * 1024 + scg];

    uint4 kreg[4], vreg[4];
    #pragma unroll
    for (int j = 0; j < 4; ++j) {
        kreg[j] = *(const uint4*)&kg[j * 8];
        vreg[j] = *(const uint4*)&vg[j * 8];
    }

    for (int i = 0; i < 16; ++i) {
        __syncthreads();
        #pragma unroll
        for (int j = 0; j < 4; ++j) {
            *(uint4*)&Ks[sh][srow * KSTR + scg + j * 8] = kreg[j];
            *(uint4*)&Vt[sh][srow * KSTR + scg + j * 8] = vreg[j];
        }
        __syncthreads();
        if (i + 1 < 16) {   // register prefetch of next chunk
            const ushort_t* kp = kg + (size_t)(i + 1) * 64 * 64;
            const ushort_t* vp = vg + (size_t)(i + 1) * 64;
            #pragma unroll
            for (int j = 0; j < 4; ++j) {
                kreg[j] = *(const uint4*)&kp[j * 8];
                vreg[j] = *(const uint4*)&vp[j * 8];
            }
        }

        const int kci = kh * 16 + i;
        const int mbase = b * S_ + kci * 64;
        // ---- S^T = K Q^T per 32-key tile; p = exp(s+bias); packed b64 P ----
        #pragma unroll
        for (int mt = 0; mt < 2; ++mt) {
            f32x16 s;
            #pragma unroll
            for (int ii = 0; ii < 16; ++ii) s[ii] = 0.f;
            #pragma unroll
            for (int ksl = 0; ksl < 4; ++ksl) {
                half8 ak = *(const half8*)&Ks[kh][(mt * 32 + lm) * KSTR + ksl * 16 + hh * 8];
                s = __builtin_amdgcn_mfma_f32_32x32x16_f16(ak, qfr[ksl], s, 0, 0, 0);
            }
            #pragma unroll
            for (int g = 0; g < 4; ++g) {
                int4 mi = *(const int4*)&mask[mbase + mt * 32 + g * 8 + hh * 4];
                float p0 = __expf(s[g * 4 + 0] + (mi.x ? -64.f : -1e30f));
                float p1 = __expf(s[g * 4 + 1] + (mi.y ? -64.f : -1e30f));
                float p2 = __expf(s[g * 4 + 2] + (mi.z ? -64.f : -1e30f));
                float p3 = __expf(s[g * 4 + 3] + (mi.w ? -64.f : -1e30f));
                ls += (p0 + p1) + (p2 + p3);
                ushort_t p4[4] = {f2bs_fast(p0), f2bs_fast(p1), f2bs_fast(p2), f2bs_fast(p3)};
                *(uint2*)&Ps[w][lm * KSTR + mt * 32 + g * 8 + hh * 4] = *(uint2*)p4;
            }
        }
        __asm__ volatile("s_waitcnt lgkmcnt(0)" ::: "memory");

        // ---- O += P V ----
        #pragma unroll
        for (int ksl = 0; ksl < 4; ++ksl) {
            short8 ap = *(const short8*)&Ps[w][lm * KSTR + ksl * 16 + hh * 8];
            #pragma unroll
            for (int dt = 0; dt < 2; ++dt) {
                short8 bv = *(const short8*)&Vt[kh][(dt * 32 + lm) * KSTR + ksl * 16 + hh * 8];
                acc[dt] = __builtin_amdgcn_mfma_f32_32x32x16_bf16(ap, bv, acc[dt], 0, 0, 0);
            }
        }
    }

    // ---- combine key-halves (fixed shift => plain add), normalize, store ----
    ls += __shfl_xor(ls, 32);
    __syncthreads();   // all waves done with Ks/Vt/Ps
    if (kh == 1) {
        #pragma unroll
        for (int dt = 0; dt < 2; ++dt)
            #pragma unroll
            for (int r = 0; r < 16; ++r) {
                int ql = (r & 3) + 8 * (r >> 2) + 4 * hh;
                cbO[qsub][ql][dt * 32 + lm] = acc[dt][r];
            }
        if (hh == 0) cbL[qsub][lm] = ls;
    }
    __syncthreads();
    if (kh == 0) {
        float lt = ls + cbL[qsub][lm];
        linv[qsub][lm] = 1.f / lt;
        __asm__ volatile("s_waitcnt lgkmcnt(0)" ::: "memory");
        float li[16];
        #pragma unroll
        for (int r = 0; r < 16; ++r) li[r] = linv[qsub][(r & 3) + 8 * (r >> 2) + 4 * hh];
        #pragma unroll
        for (int dt = 0; dt < 2; ++dt)
            #pragma unroll
            for (int r = 0; r < 16; ++r) {
                int ql = (r & 3) + 8 * (r >> 2) + 4 * hh;
                float o = acc[dt][r] + cbO[qsub][ql][dt * 32 + lm];
                int s = q0 + ql;
                int d = dt * 32 + lm;
                ctx[((size_t)b * S_ + s) * E_ + hd * D_ + d] = f2bs(o * li[r]);
            }
    }
}

// ---------------- Kernel 3: out = ctx @ Wo^T + bo (bf16 Wo from prep) ----------------
__global__ void __launch_bounds__(256) outproj_mfma(
    const ushort_t* __restrict__ ctx, const ushort_t* __restrict__ wob,
    const float* __restrict__ bo, float* __restrict__ out)
{
    __shared__ ushort_t As[64 * 72];
    __shared__ ushort_t Bs[64 * 72];
    const int m0 = blockIdx.x * 64, n0 = blockIdx.y * 64;
    const int t = threadIdx.x;
    const int w = t >> 6, lm = t & 15, quad = (t >> 4) & 3;

    f32x4 acc[4];
    #pragma unroll
    for (int nt = 0; nt < 4; ++nt) acc[nt] = (f32x4){0.f, 0.f, 0.f, 0.f};

    for (int kc = 0; kc < E_ / 64; ++kc) {
        __syncthreads();
        {   // A: ctx rows (bf16)
            int row = t >> 2, cg = (t & 3) * 16;
            const ushort_t* g = ctx + (size_t)(m0 + row) * E_ + kc * 64 + cg;
            *(uint4*)&As[row * 72 + cg]     = *(const uint4*)g;
            *(uint4*)&As[row * 72 + cg + 8] = *(const uint4*)(g + 8);
        }
        {   // B: wob rows (bf16, pre-converted)
            int n = t >> 2, kg2 = (t & 3) * 16;
            const ushort_t* g = &wob[(size_t)(n0 + n) * E_ + kc * 64 + kg2];
            *(uint4*)&Bs[n * 72 + kg2]     = *(const uint4*)g;
            *(uint4*)&Bs[n * 72 + kg2 + 8] = *(const uint4*)(g + 8);
        }
        __syncthreads();

        #pragma unroll
        for (int kk = 0; kk < 2; ++kk) {
            short8 a = *(const short8*)&As[(w * 16 + lm) * 72 + kk * 32 + quad * 8];
            #pragma unroll
            for (int nt = 0; nt < 4; ++nt) {
                short8 bb = *(const short8*)&Bs[(nt * 16 + lm) * 72 + kk * 32 + quad * 8];
                acc[nt] = __builtin_amdgcn_mfma_f32_16x16x32_bf16(a, bb, acc[nt], 0, 0, 0);
            }
        }
    }

    #pragma unroll
    for (int nt = 0; nt < 4; ++nt) {
        float bias = bo[n0 + nt * 16 + lm];
        #pragma unroll
        for (int r = 0; r < 4; ++r) {
            int m = m0 + w * 16 + quad * 4 + r;
            out[(size_t)m * E_ + n0 + nt * 16 + lm] = acc[nt][r] + bias;
        }
    }
}

extern "C" void kernel_launch(void* const* d_in, const int* in_sizes, int n_in,
                              void* d_out, int out_size, void* d_ws, size_t ws_size,
                              hipStream_t stream) {
    const float* vals = (const float*)d_in[0];
    const float* keys = (const float*)d_in[1];
    const float* quer = (const float*)d_in[2];
    const int*   mask = (const int*)d_in[3];
    const float* Wv   = (const float*)d_in[4];
    const float* Wo   = (const float*)d_in[5];
    const float* bo   = (const float*)d_in[6];
    float* out = (float*)d_out;

    const size_t N = (size_t)B_ * H_ * S_ * D_;   // 2097152
    ushort_t* ws  = (ushort_t*)d_ws;
    ushort_t* qf  = ws;                 // fp16 (bh, s, d)
    ushort_t* kf  = ws + N;             // fp16 (bh, s, d)
    ushort_t* vt  = ws + 2 * N;         // bf16 (bh, d, s)
    ushort_t* ctx = ws + 3 * N;         // bf16 (b, s, E)
    ushort_t* wvh = ws + 4 * N;         // bf16 4096
    ushort_t* wvl = wvh + 4096;         // bf16 4096
    ushort_t* wob = wvl + 4096;         // bf16 262144

    prep_kernel<<<256, 256, 0, stream>>>(Wv, Wo, wvh, wvl, wob);
    proj_mfma<<<dim3(B_ * H_ * (S_ / 64), 3), 256, 0, stream>>>(
        quer, keys, vals, wvh, wvl, qf, kf, vt);
    attn_mfma<<<B_ * H_ * (S_ / 64), 256, 0, stream>>>(qf, kf, vt, mask, ctx);
    outproj_mfma<<<dim3((B_ * S_) / 64, E_ / 64), 256, 0, stream>>>(ctx, wob, bo, out);
}

// Round 11
// 187.575 us; speedup vs baseline: 1.0512x; 1.0212x over previous
//
#include <hip/hip_runtime.h>

// MultiHeadSelfAttention  B=2 S=2048 E=512 H=8 D=64, fp32 in/out.
// R11 = R10 with ONE change: attn __launch_bounds__(256, 2).
//   R10 post-mortem: WRITE_SIZE=172MB (vs 4MB output) = scratch spills; the
//   compiler capped VGPR at 88 targeting 5 waves/SIMD, but LDS (72KB, 2
//   blocks/CU) caps occupancy at 2 waves/SIMD anyway. Declaring (256,2)
//   raises the VGPR budget to 256/wave -> no spills.
// Structure: 32x32x16 attn engine, key-split waves (qsub x keyhalf), fixed-
//   shift softmax (linear => end combine), prep kernel pre-splits Wv / converts Wo.
// Layouts (HW-verified): 16x16 A[m=lane&15][k=quad*8+j], D[row=quad*4+reg][col=lane&15];
//   32x32 C/D col=lane&31, row=(reg&3)+8*(reg>>2)+4*(lane>>5); A/B k=(lane>>5)*8+j.

#define B_ 2
#define S_ 2048
#define E_ 512
#define H_ 8
#define D_ 64

typedef unsigned short ushort_t;
typedef __attribute__((ext_vector_type(8))) short short8;
typedef __attribute__((ext_vector_type(8))) _Float16 half8;
typedef __attribute__((ext_vector_type(4))) float f32x4;
typedef __attribute__((ext_vector_type(16))) float f32x16;

__device__ __forceinline__ ushort_t f2bs(float x) {   // fp32 -> bf16, RNE
    union { float f; unsigned int u; } a; a.f = x;
    unsigned int u = a.u;
    u += 0x7fffu + ((u >> 16) & 1u);
    return (ushort_t)(u >> 16);
}
__device__ __forceinline__ ushort_t f2bs_fast(float x) {   // round-half-up (P only)
    union { float f; unsigned int u; } a; a.f = x;
    return (ushort_t)((a.u + 0x8000u) >> 16);
}
__device__ __forceinline__ float bs2f(ushort_t h) {
    union { unsigned int u; float f; } a; a.u = ((unsigned int)h) << 16;
    return a.f;
}
__device__ __forceinline__ ushort_t f2hs(float x) {
    _Float16 h = (_Float16)x;
    ushort_t u; __builtin_memcpy(&u, &h, 2);
    return u;
}
__device__ __forceinline__ void split16(const float4* g, ushort_t* hi, ushort_t* lo) {
    #pragma unroll
    for (int q = 0; q < 4; ++q) {
        float4 f = g[q];
        float vv[4] = {f.x, f.y, f.z, f.w};
        #pragma unroll
        for (int j = 0; j < 4; ++j) {
            ushort_t h = f2bs(vv[j]);
            hi[q * 4 + j] = h;
            lo[q * 4 + j] = f2bs(vv[j] - bs2f(h));
        }
    }
}

// ---------------- Kernel 0: weight prep (once) ----------------
__global__ void __launch_bounds__(256) prep_kernel(
    const float* __restrict__ Wv, const float* __restrict__ Wo,
    ushort_t* __restrict__ wvh, ushort_t* __restrict__ wvl,
    ushort_t* __restrict__ wob)
{
    const int t = threadIdx.x;
    size_t base = ((size_t)blockIdx.x * 256 + t) * 4;   // Wo: 262144 = 256*256*4
    float4 f = *(const float4*)&Wo[base];
    ushort_t o4[4] = {f2bs(f.x), f2bs(f.y), f2bs(f.z), f2bs(f.w)};
    *(uint2*)&wob[base] = *(uint2*)o4;
    if (blockIdx.x == 0) {
        ushort_t hi[16], lo[16];
        split16((const float4*)(Wv + t * 16), hi, lo);
        *(uint4*)&wvh[t * 16]     = *(uint4*)hi;
        *(uint4*)&wvh[t * 16 + 8] = *(uint4*)(hi + 8);
        *(uint4*)&wvl[t * 16]     = *(uint4*)lo;
        *(uint4*)&wvl[t * 16 + 8] = *(uint4*)(lo + 8);
    }
}

// ---------------- Kernel 1: split-precision projection ----------------
__global__ void __launch_bounds__(256) proj_mfma(
    const float* __restrict__ quer, const float* __restrict__ keys,
    const float* __restrict__ vals,
    const ushort_t* __restrict__ wvh, const ushort_t* __restrict__ wvl,
    ushort_t* __restrict__ qf, ushort_t* __restrict__ kf,
    ushort_t* __restrict__ vt)
{
    __shared__ ushort_t Ah[64 * 72], Al[64 * 72];
    __shared__ ushort_t Bh[64 * 72], Bl[64 * 72];
    const int tens = blockIdx.y;
    const float* src = tens == 0 ? quer : (tens == 1 ? keys : vals);
    const int bx = blockIdx.x;            // bh*32 + st
    const int st = bx & 31, bh = bx >> 5;
    const int b = bh >> 3, h = bh & 7;
    const int s0 = st * 64;
    const int t = threadIdx.x;

    {   // Bh/Bl [e][d] from pre-split global (plain copies)
        int e = t >> 2, dg = (t & 3) * 16;
        size_t wad = (size_t)e * 64 + dg;
        *(uint4*)&Bh[e * 72 + dg]     = *(const uint4*)&wvh[wad];
        *(uint4*)&Bh[e * 72 + dg + 8] = *(const uint4*)&wvh[wad + 8];
        *(uint4*)&Bl[e * 72 + dg]     = *(const uint4*)&wvl[wad];
        *(uint4*)&Bl[e * 72 + dg + 8] = *(const uint4*)&wvl[wad + 8];
    }
    {   // x rows (s0..s0+63) -> Ah/Al [s][d] (split in regs)
        int row = t >> 2, cg = (t & 3) * 16;
        const float* g = src + ((size_t)b * S_ + s0 + row) * 512 + h * 64 + cg;
        ushort_t th[16], tl[16];
        split16((const float4*)g, th, tl);
        *(uint4*)&Ah[row * 72 + cg] = *(uint4*)th;  *(uint4*)&Ah[row * 72 + cg + 8] = *(uint4*)(th + 8);
        *(uint4*)&Al[row * 72 + cg] = *(uint4*)tl;  *(uint4*)&Al[row * 72 + cg + 8] = *(uint4*)(tl + 8);
    }
    __syncthreads();

    const int w = t >> 6, lm = t & 15, quad = (t >> 4) & 3;
    f32x4 acc[4];
    #pragma unroll
    for (int nt = 0; nt < 4; ++nt) acc[nt] = (f32x4){0.f, 0.f, 0.f, 0.f};

    #pragma unroll
    for (int kk = 0; kk < 2; ++kk) {
        short8 ah = *(const short8*)&Ah[(w * 16 + lm) * 72 + kk * 32 + quad * 8];
        short8 al = *(const short8*)&Al[(w * 16 + lm) * 72 + kk * 32 + quad * 8];
        #pragma unroll
        for (int nt = 0; nt < 4; ++nt) {
            short8 bh8 = *(const short8*)&Bh[(nt * 16 + lm) * 72 + kk * 32 + quad * 8];
            short8 bl8 = *(const short8*)&Bl[(nt * 16 + lm) * 72 + kk * 32 + quad * 8];
            acc[nt] = __builtin_amdgcn_mfma_f32_16x16x32_bf16(ah, bh8, acc[nt], 0, 0, 0);
            acc[nt] = __builtin_amdgcn_mfma_f32_16x16x32_bf16(al, bh8, acc[nt], 0, 0, 0);
            acc[nt] = __builtin_amdgcn_mfma_f32_16x16x32_bf16(ah, bl8, acc[nt], 0, 0, 0);
        }
    }

    if (tens < 2) {       // q,k: fp16 (bh, s, d)
        ushort_t* dst = tens == 0 ? qf : kf;
        #pragma unroll
        for (int nt = 0; nt < 4; ++nt)
            #pragma unroll
            for (int r = 0; r < 4; ++r) {
                size_t addr = ((size_t)bh * S_ + s0 + w * 16 + quad * 4 + r) * 64 + nt * 16 + lm;
                dst[addr] = f2hs(acc[nt][r]);
            }
    } else {              // v: bf16 transposed (bh, d, s), 8B packed stores
        #pragma unroll
        for (int nt = 0; nt < 4; ++nt) {
            unsigned int p0 = (unsigned int)f2bs(acc[nt][0]) | ((unsigned int)f2bs(acc[nt][1]) << 16);
            unsigned int p1 = (unsigned int)f2bs(acc[nt][2]) | ((unsigned int)f2bs(acc[nt][3]) << 16);
            uint2 pk; pk.x = p0; pk.y = p1;
            size_t addr = ((size_t)bh * 64 + nt * 16 + lm) * S_ + s0 + w * 16 + quad * 4;
            *(uint2*)&vt[addr] = pk;
        }
    }
}

// ---------------- Kernel 2: flash attention (32x32x16, key-split waves) ----------------
#define KSTR 72
__global__ void __launch_bounds__(256, 2) attn_mfma(
    const ushort_t* __restrict__ qf, const ushort_t* __restrict__ kf,
    const ushort_t* __restrict__ vt, const int* __restrict__ mask,
    ushort_t* __restrict__ ctx)
{
    __shared__ ushort_t Ks[2][64 * KSTR];     // fp16 K [key][d], per key-half
    __shared__ ushort_t Vt[2][64 * KSTR];     // bf16 V [d][key], per key-half
    __shared__ ushort_t Ps[4][32 * KSTR];     // per-wave P [q][key]
    __shared__ float    cbO[2][32][64];       // kh=1 partial O per qsub
    __shared__ float    cbL[2][32];           // kh=1 partial l
    __shared__ float    linv[2][32];

    const int bx = blockIdx.x;
    const int qt = bx & 31;                   // 32 q-tiles of 64
    const int bh = bx >> 5;
    const int b  = bh >> 3, hd = bh & 7;
    const int t  = threadIdx.x;
    const int w  = t >> 6;
    const int qsub = w & 1, kh = w >> 1;
    const int lane = t & 63;
    const int lm = lane & 31;
    const int hh = lane >> 5;
    const int q0 = qt * 64 + qsub * 32;

    // Q B-frags, held all kernel
    half8 qfr[4];
    {
        size_t base = ((size_t)bh * S_ + q0 + lm) * 64 + hh * 8;
        #pragma unroll
        for (int ksl = 0; ksl < 4; ++ksl)
            qfr[ksl] = *(const half8*)&qf[base + ksl * 16];
    }

    f32x16 acc[2];
    #pragma unroll
    for (int dt = 0; dt < 2; ++dt)
        #pragma unroll
        for (int i = 0; i < 16; ++i) acc[dt][i] = 0.f;
    float ls = 0.f;

    // staging: first 128 threads stage half 0, next 128 stage half 1
    const int sh = t >> 7;
    const int tt = t & 127;
    const int srow = tt >> 1, scg = (tt & 1) * 32;
    const ushort_t* kg = &kf[((size_t)bh * S_ + sh * 1024 + srow) * 64 + scg];
    const ushort_t* vg = &vt[((size_t)bh * 64 + srow) * S_ + sh * 1024 + scg];

    uint4 kreg[4], vreg[4];
    #pragma unroll
    for (int j = 0; j < 4; ++j) {
        kreg[j] = *(const uint4*)&kg[j * 8];
        vreg[j] = *(const uint4*)&vg[j * 8];
    }

    for (int i = 0; i < 16; ++i) {
        __syncthreads();
        #pragma unroll
        for (int j = 0; j < 4; ++j) {
            *(uint4*)&Ks[sh][srow * KSTR + scg + j * 8] = kreg[j];
            *(uint4*)&Vt[sh][srow * KSTR + scg + j * 8] = vreg[j];
        }
        __syncthreads();
        if (i + 1 < 16) {   // register prefetch of next chunk
            const ushort_t* kp = kg + (size_t)(i + 1) * 64 * 64;
            const ushort_t* vp = vg + (size_t)(i + 1) * 64;
            #pragma unroll
            for (int j = 0; j < 4; ++j) {
                kreg[j] = *(const uint4*)&kp[j * 8];
                vreg[j] = *(const uint4*)&vp[j * 8];
            }
        }

        const int kci = kh * 16 + i;
        const int mbase = b * S_ + kci * 64;
        // ---- S^T = K Q^T per 32-key tile; p = exp(s+bias); packed b64 P ----
        #pragma unroll
        for (int mt = 0; mt < 2; ++mt) {
            f32x16 s;
            #pragma unroll
            for (int ii = 0; ii < 16; ++ii) s[ii] = 0.f;
            #pragma unroll
            for (int ksl = 0; ksl < 4; ++ksl) {
                half8 ak = *(const half8*)&Ks[kh][(mt * 32 + lm) * KSTR + ksl * 16 + hh * 8];
                s = __builtin_amdgcn_mfma_f32_32x32x16_f16(ak, qfr[ksl], s, 0, 0, 0);
            }
            #pragma unroll
            for (int g = 0; g < 4; ++g) {
                int4 mi = *(const int4*)&mask[mbase + mt * 32 + g * 8 + hh * 4];
                float p0 = __expf(s[g * 4 + 0] + (mi.x ? -64.f : -1e30f));
                float p1 = __expf(s[g * 4 + 1] + (mi.y ? -64.f : -1e30f));
                float p2 = __expf(s[g * 4 + 2] + (mi.z ? -64.f : -1e30f));
                float p3 = __expf(s[g * 4 + 3] + (mi.w ? -64.f : -1e30f));
                ls += (p0 + p1) + (p2 + p3);
                ushort_t p4[4] = {f2bs_fast(p0), f2bs_fast(p1), f2bs_fast(p2), f2bs_fast(p3)};
                *(uint2*)&Ps[w][lm * KSTR + mt * 32 + g * 8 + hh * 4] = *(uint2*)p4;
            }
        }
        __asm__ volatile("s_waitcnt lgkmcnt(0)" ::: "memory");

        // ---- O += P V ----
        #pragma unroll
        for (int ksl = 0; ksl < 4; ++ksl) {
            short8 ap = *(const short8*)&Ps[w][lm * KSTR + ksl * 16 + hh * 8];
            #pragma unroll
            for (int dt = 0; dt < 2; ++dt) {
                short8 bv = *(const short8*)&Vt[kh][(dt * 32 + lm) * KSTR + ksl * 16 + hh * 8];
                acc[dt] = __builtin_amdgcn_mfma_f32_32x32x16_bf16(ap, bv, acc[dt], 0, 0, 0);
            }
        }
    }

    // ---- combine key-halves (fixed shift => plain add), normalize, store ----
    ls += __shfl_xor(ls, 32);
    __syncthreads();   // all waves done with Ks/Vt/Ps
    if (kh == 1) {
        #pragma unroll
        for (int dt = 0; dt < 2; ++dt)
            #pragma unroll
            for (int r = 0; r < 16; ++r) {
                int ql = (r & 3) + 8 * (r >> 2) + 4 * hh;
                cbO[qsub][ql][dt * 32 + lm] = acc[dt][r];
            }
        if (hh == 0) cbL[qsub][lm] = ls;
    }
    __syncthreads();
    if (kh == 0) {
        float lt = ls + cbL[qsub][lm];
        linv[qsub][lm] = 1.f / lt;
        __asm__ volatile("s_waitcnt lgkmcnt(0)" ::: "memory");
        float li[16];
        #pragma unroll
        for (int r = 0; r < 16; ++r) li[r] = linv[qsub][(r & 3) + 8 * (r >> 2) + 4 * hh];
        #pragma unroll
        for (int dt = 0; dt < 2; ++dt)
            #pragma unroll
            for (int r = 0; r < 16; ++r) {
                int ql = (r & 3) + 8 * (r >> 2) + 4 * hh;
                float o = acc[dt][r] + cbO[qsub][ql][dt * 32 + lm];
                int s = q0 + ql;
                int d = dt * 32 + lm;
                ctx[((size_t)b * S_ + s) * E_ + hd * D_ + d] = f2bs(o * li[r]);
            }
    }
}

// ---------------- Kernel 3: out = ctx @ Wo^T + bo (bf16 Wo from prep) ----------------
__global__ void __launch_bounds__(256) outproj_mfma(
    const ushort_t* __restrict__ ctx, const ushort_t* __restrict__ wob,
    const float* __restrict__ bo, float* __restrict__ out)
{
    __shared__ ushort_t As[64 * 72];
    __shared__ ushort_t Bs[64 * 72];
    const int m0 = blockIdx.x * 64, n0 = blockIdx.y * 64;
    const int t = threadIdx.x;
    const int w = t >> 6, lm = t & 15, quad = (t >> 4) & 3;

    f32x4 acc[4];
    #pragma unroll
    for (int nt = 0; nt < 4; ++nt) acc[nt] = (f32x4){0.f, 0.f, 0.f, 0.f};

    for (int kc = 0; kc < E_ / 64; ++kc) {
        __syncthreads();
        {   // A: ctx rows (bf16)
            int row = t >> 2, cg = (t & 3) * 16;
            const ushort_t* g = ctx + (size_t)(m0 + row) * E_ + kc * 64 + cg;
            *(uint4*)&As[row * 72 + cg]     = *(const uint4*)g;
            *(uint4*)&As[row * 72 + cg + 8] = *(const uint4*)(g + 8);
        }
        {   // B: wob rows (bf16, pre-converted)
            int n = t >> 2, kg2 = (t & 3) * 16;
            const ushort_t* g = &wob[(size_t)(n0 + n) * E_ + kc * 64 + kg2];
            *(uint4*)&Bs[n * 72 + kg2]     = *(const uint4*)g;
            *(uint4*)&Bs[n * 72 + kg2 + 8] = *(const uint4*)(g + 8);
        }
        __syncthreads();

        #pragma unroll
        for (int kk = 0; kk < 2; ++kk) {
            short8 a = *(const short8*)&As[(w * 16 + lm) * 72 + kk * 32 + quad * 8];
            #pragma unroll
            for (int nt = 0; nt < 4; ++nt) {
                short8 bb = *(const short8*)&Bs[(nt * 16 + lm) * 72 + kk * 32 + quad * 8];
                acc[nt] = __builtin_amdgcn_mfma_f32_16x16x32_bf16(a, bb, acc[nt], 0, 0, 0);
            }
        }
    }

    #pragma unroll
    for (int nt = 0; nt < 4; ++nt) {
        float bias = bo[n0 + nt * 16 + lm];
        #pragma unroll
        for (int r = 0; r < 4; ++r) {
            int m = m0 + w * 16 + quad * 4 + r;
            out[(size_t)m * E_ + n0 + nt * 16 + lm] = acc[nt][r] + bias;
        }
    }
}

extern "C" void kernel_launch(void* const* d_in, const int* in_sizes, int n_in,
                              void* d_out, int out_size, void* d_ws, size_t ws_size,
                              hipStream_t stream) {
    const float* vals = (const float*)d_in[0];
    const float* keys = (const float*)d_in[1];
    const float* quer = (const float*)d_in[2];
    const int*   mask = (const int*)d_in[3];
    const float* Wv   = (const float*)d_in[4];
    const float* Wo   = (const float*)d_in[5];
    const float* bo   = (const float*)d_in[6];
    float* out = (float*)d_out;

    const size_t N = (size_t)B_ * H_ * S_ * D_;   // 2097152
    ushort_t* ws  = (ushort_t*)d_ws;
    ushort_t* qf  = ws;                 // fp16 (bh, s, d)
    ushort_t* kf  = ws + N;             // fp16 (bh, s, d)
    ushort_t* vt  = ws + 2 * N;         // bf16 (bh, d, s)
    ushort_t* ctx = ws + 3 * N;         // bf16 (b, s, E)
    ushort_t* wvh = ws + 4 * N;         // bf16 4096
    ushort_t* wvl = wvh + 4096;         // bf16 4096
    ushort_t* wob = wvl + 4096;         // bf16 262144

    prep_kernel<<<256, 256, 0, stream>>>(Wv, Wo, wvh, wvl, wob);
    proj_mfma<<<dim3(B_ * H_ * (S_ / 64), 3), 256, 0, stream>>>(
        quer, keys, vals, wvh, wvl, qf, kf, vt);
    attn_mfma<<<B_ * H_ * (S_ / 64), 256, 0, stream>>>(qf, kf, vt, mask, ctx);
    outproj_mfma<<<dim3((B_ * S_) / 64, E_ / 64), 256, 0, stream>>>(ctx, wob, bo, out);
}